// Round 10
// baseline (89.190 us; speedup 1.0000x reference)
//
#include <hip/hip_runtime.h>
#include <math.h>

constexpr int H = 2048;
constexpr int W = 4096;
constexpr int RS = W * 3;   // floats per image row

// window: 12 rows x 72 px (216 dwords used, stride 220 dwords = 880 B)
constexpr int WIN_ROWS = 12;
constexpr int WIN_STRIDE = 220;

__device__ __forceinline__ float k_inner(float t) {   // t in [0,1]
    return fmaf(fmaf(1.5f, t, -2.5f), t * t, 1.0f);
}
__device__ __forceinline__ float k_outer(float t) {   // t in [1,2]
    return fmaf(fmaf(fmaf(-0.5f, t, 2.5f), t, -4.0f), t, 2.0f);
}
__device__ __forceinline__ float cubic_w(float t) {
    float at = fabsf(t);
    if (at <= 1.0f) return k_inner(at);
    if (at < 2.0f)  return k_outer(at);
    return 0.0f;
}

__device__ __forceinline__ void row_cy(int h, const float* __restrict__ dctrl, float cy[6]) {
    float u = (float)(2 * h) / (float)(H - 1);
    float i0 = floorf(u);
    float by0 = 0.f, by1 = 0.f, by2 = 0.f;
#pragma unroll
    for (int k = -1; k < 3; ++k) {
        float tap = i0 + (float)k;
        float wt = cubic_w(u - tap);
        int tc = (int)tap;
        tc = tc < 0 ? 0 : (tc > 2 ? 2 : tc);
        if (tc == 0) by0 += wt; else if (tc == 1) by1 += wt; else by2 += wt;
    }
#pragma unroll
    for (int x = 0; x < 3; ++x) {
        cy[x]     = 5.0f * (by0 * dctrl[x]     + by1 * dctrl[3 + x]  + by2 * dctrl[6 + x]);
        cy[3 + x] = 5.0f * (by0 * dctrl[9 + x] + by1 * dctrl[12 + x] + by2 * dctrl[15 + x]);
    }
}

__device__ __forceinline__ void bx3(int w, float& b0, float& b1, float& b2) {
    float u = (float)w * (2.0f / 4095.0f);
    bool hiu = u >= 1.0f;
    float s = u - (hiu ? 1.0f : 0.0f);
    float o1 = k_outer(1.0f + s);
    float is = k_inner(s);
    float i1 = k_inner(1.0f - s);
    float o2 = k_outer(2.0f - s);
    b0 = hiu ? o1 : (o1 + is);
    b1 = hiu ? is : i1;
    b2 = hiu ? (i1 + o2) : o2;
}

// Block = 64x4 px tile (wave = one output row of 64 px).
__global__ __launch_bounds__(256)
void elastic_warp_kernel(const float* __restrict__ img,
                         const float* __restrict__ dctrl,  // (2,3,3) unscaled
                         float* __restrict__ out) {
    int x0 = blockIdx.x << 6;
    int y0 = blockIdx.y << 2;
    int t = threadIdx.x;
    int r = t >> 6;            // 0..3 tile row
    int w = x0 + (t & 63);
    int h = y0 + r;

    __shared__ float s_cy[4][6];
    __shared__ int   s_base[2];
    __shared__ int   s_flag[4];
    __shared__ float s_win[WIN_ROWS][WIN_STRIDE];   // ~10.6 KB

    if (t < 4) {
        float cy[6];
        row_cy(y0 + t, dctrl, cy);
#pragma unroll
        for (int j = 0; j < 6; ++j) s_cy[t][j] = cy[j];
        if (t == 0) {
            float b0, b1, b2; bx3(x0, b0, b1, b2);
            float d0 = cy[0]*b0 + cy[1]*b1 + cy[2]*b2;
            float d1 = cy[3]*b0 + cy[4]*b1 + cy[5]*b2;
            s_base[0] = (int)floorf((float)y0 + d0);
            s_base[1] = (int)floorf((float)x0 + d1);
        }
    }
    __syncthreads();

    float cy0 = s_cy[r][0], cy1 = s_cy[r][1], cy2 = s_cy[r][2];
    float cy3 = s_cy[r][3], cy4 = s_cy[r][4], cy5 = s_cy[r][5];
    int base_iy = s_base[0], base_ix = s_base[1];

    float bx0, bx1, bx2; bx3(w, bx0, bx1, bx2);
    float d0 = cy0*bx0 + cy1*bx1 + cy2*bx2;
    float d1 = cy3*bx0 + cy4*bx1 + cy5*bx2;

    float yy = (float)h + d0;
    float xx = (float)w + d1;
    float fly = floorf(yy), flx = floorf(xx);
    float fy = yy - fly, fx = xx - flx;
    int iy0 = (int)fly, ix0 = (int)flx;

    // window anchor (all block-uniform)
    int yb = base_iy - 2;                 // staged rows yb .. yb+11
    int xb = (base_ix - 2) & ~3;          // staged cols xb .. xb+71 (16B-aligned)

    int ry0 = iy0 - 1 - yb;               // first tap row within window
    int cxp = ix0 - 1 - xb;               // first tap col (px) within window

    bool uok = (yb >= 0) & (yb + WIN_ROWS - 1 <= H - 1) & (xb >= 0) & (xb + 71 <= W - 1);
    bool lok = (ry0 >= 0) & (ry0 <= 8) & (cxp >= 0) & (cxp <= 68);
    int wflag = __all(uok & lok);
    if ((t & 63) == 0) s_flag[t >> 6] = wflag;
    __syncthreads();
    bool fast = s_flag[0] && s_flag[1] && s_flag[2] && s_flag[3];

    float wy0 = k_outer(1.0f + fy), wy1 = k_inner(fy), wy2 = k_inner(1.0f - fy), wy3 = k_outer(2.0f - fy);
    float wx0 = k_outer(1.0f + fx), wx1 = k_inner(fx), wx2 = k_inner(1.0f - fx), wx3 = k_outer(2.0f - fx);

    float acc0 = 0.f, acc1 = 0.f, acc2 = 0.f;

    if (fast) {
        // ---- cooperative stage: 12 rows x 54 float4 = 648 ----
        const float* gbase = img + yb * RS + xb * 3;
#pragma unroll
        for (int it = 0; it < 3; ++it) {
            int idx = t + (it << 8);
            if (idx < 648) {
                int row = idx / 54;
                int c4  = idx - row * 54;
                float4 v = *(const float4*)(gbase + row * RS + (c4 << 2));
                *(float4*)&s_win[row][c4 << 2] = v;
            }
        }
        __syncthreads();

        // ---- gather 4 rows x 12 dwords via ds_read2_b32 (24 DS instrs) ----
        int cxd = cxp * 3;
        unsigned ad0 = (unsigned)(uintptr_t)&s_win[ry0][cxd];
        unsigned ad1 = ad0 + 4 * WIN_STRIDE;
        unsigned ad2 = ad0 + 8 * WIN_STRIDE;
        unsigned ad3 = ad0 + 12 * WIN_STRIDE;

        float2 g00, g01, g02, g03, g04, g05;
        float2 g10, g11, g12, g13, g14, g15;
        float2 g20, g21, g22, g23, g24, g25;
        float2 g30, g31, g32, g33, g34, g35;
        asm volatile(
            "ds_read2_b32 %0,  %24 offset0:0 offset1:3\n\t"
            "ds_read2_b32 %1,  %24 offset0:1 offset1:4\n\t"
            "ds_read2_b32 %2,  %24 offset0:2 offset1:5\n\t"
            "ds_read2_b32 %3,  %24 offset0:6 offset1:9\n\t"
            "ds_read2_b32 %4,  %24 offset0:7 offset1:10\n\t"
            "ds_read2_b32 %5,  %24 offset0:8 offset1:11\n\t"
            "ds_read2_b32 %6,  %25 offset0:0 offset1:3\n\t"
            "ds_read2_b32 %7,  %25 offset0:1 offset1:4\n\t"
            "ds_read2_b32 %8,  %25 offset0:2 offset1:5\n\t"
            "ds_read2_b32 %9,  %25 offset0:6 offset1:9\n\t"
            "ds_read2_b32 %10, %25 offset0:7 offset1:10\n\t"
            "ds_read2_b32 %11, %25 offset0:8 offset1:11\n\t"
            "ds_read2_b32 %12, %26 offset0:0 offset1:3\n\t"
            "ds_read2_b32 %13, %26 offset0:1 offset1:4\n\t"
            "ds_read2_b32 %14, %26 offset0:2 offset1:5\n\t"
            "ds_read2_b32 %15, %26 offset0:6 offset1:9\n\t"
            "ds_read2_b32 %16, %26 offset0:7 offset1:10\n\t"
            "ds_read2_b32 %17, %26 offset0:8 offset1:11\n\t"
            "ds_read2_b32 %18, %27 offset0:0 offset1:3\n\t"
            "ds_read2_b32 %19, %27 offset0:1 offset1:4\n\t"
            "ds_read2_b32 %20, %27 offset0:2 offset1:5\n\t"
            "ds_read2_b32 %21, %27 offset0:6 offset1:9\n\t"
            "ds_read2_b32 %22, %27 offset0:7 offset1:10\n\t"
            "ds_read2_b32 %23, %27 offset0:8 offset1:11\n\t"
            "s_waitcnt lgkmcnt(0)"
            : "=&v"(g00), "=&v"(g01), "=&v"(g02), "=&v"(g03), "=&v"(g04), "=&v"(g05),
              "=&v"(g10), "=&v"(g11), "=&v"(g12), "=&v"(g13), "=&v"(g14), "=&v"(g15),
              "=&v"(g20), "=&v"(g21), "=&v"(g22), "=&v"(g23), "=&v"(g24), "=&v"(g25),
              "=&v"(g30), "=&v"(g31), "=&v"(g32), "=&v"(g33), "=&v"(g34), "=&v"(g35)
            : "v"(ad0), "v"(ad1), "v"(ad2), "v"(ad3)
            : "memory");

        float q0, q1, q2, q3;
        q0 = wy0 * wx0; q1 = wy0 * wx1; q2 = wy0 * wx2; q3 = wy0 * wx3;
        acc0 = fmaf(q0, g00.x, fmaf(q1, g00.y, fmaf(q2, g03.x, fmaf(q3, g03.y, acc0))));
        acc1 = fmaf(q0, g01.x, fmaf(q1, g01.y, fmaf(q2, g04.x, fmaf(q3, g04.y, acc1))));
        acc2 = fmaf(q0, g02.x, fmaf(q1, g02.y, fmaf(q2, g05.x, fmaf(q3, g05.y, acc2))));

        q0 = wy1 * wx0; q1 = wy1 * wx1; q2 = wy1 * wx2; q3 = wy1 * wx3;
        acc0 = fmaf(q0, g10.x, fmaf(q1, g10.y, fmaf(q2, g13.x, fmaf(q3, g13.y, acc0))));
        acc1 = fmaf(q0, g11.x, fmaf(q1, g11.y, fmaf(q2, g14.x, fmaf(q3, g14.y, acc1))));
        acc2 = fmaf(q0, g12.x, fmaf(q1, g12.y, fmaf(q2, g15.x, fmaf(q3, g15.y, acc2))));

        q0 = wy2 * wx0; q1 = wy2 * wx1; q2 = wy2 * wx2; q3 = wy2 * wx3;
        acc0 = fmaf(q0, g20.x, fmaf(q1, g20.y, fmaf(q2, g23.x, fmaf(q3, g23.y, acc0))));
        acc1 = fmaf(q0, g21.x, fmaf(q1, g21.y, fmaf(q2, g24.x, fmaf(q3, g24.y, acc1))));
        acc2 = fmaf(q0, g22.x, fmaf(q1, g22.y, fmaf(q2, g25.x, fmaf(q3, g25.y, acc2))));

        q0 = wy3 * wx0; q1 = wy3 * wx1; q2 = wy3 * wx2; q3 = wy3 * wx3;
        acc0 = fmaf(q0, g30.x, fmaf(q1, g30.y, fmaf(q2, g33.x, fmaf(q3, g33.y, acc0))));
        acc1 = fmaf(q0, g31.x, fmaf(q1, g31.y, fmaf(q2, g34.x, fmaf(q3, g34.y, acc1))));
        acc2 = fmaf(q0, g32.x, fmaf(q1, g32.y, fmaf(q2, g35.x, fmaf(q3, g35.y, acc2))));
    } else {
        // uniform slow path: per-px clamped global gather
        float wy[4] = {wy0, wy1, wy2, wy3};
        float wx[4] = {wx0, wx1, wx2, wx3};
#pragma unroll
        for (int a = 0; a < 4; ++a) {
            int ty = iy0 + a - 1;
            ty = ty < 0 ? 0 : (ty > H - 1 ? H - 1 : ty);
            int rowoff = ty * RS;
            float ay = wy[a];
#pragma unroll
            for (int b = 0; b < 4; ++b) {
                int tx = ix0 + b - 1;
                tx = tx < 0 ? 0 : (tx > W - 1 ? W - 1 : tx);
                float wgt = ay * wx[b];
                const float* p = img + rowoff + tx * 3;
                acc0 += wgt * p[0];
                acc1 += wgt * p[1];
                acc2 += wgt * p[2];
            }
        }
    }

    int oo = (h * W + w) * 3;
    out[oo + 0] = acc0;
    out[oo + 1] = acc1;
    out[oo + 2] = acc2;
}

extern "C" void kernel_launch(void* const* d_in, const int* in_sizes, int n_in,
                              void* d_out, int out_size, void* d_ws, size_t ws_size,
                              hipStream_t stream) {
    const float* img   = (const float*)d_in[0];
    const float* dctrl = (const float*)d_in[1];
    float* out = (float*)d_out;

    dim3 grid(W / 64, H / 4);
    elastic_warp_kernel<<<grid, 256, 0, stream>>>(img, dctrl, out);
}

// Round 11
// 76.770 us; speedup vs baseline: 1.1618x; 1.1618x over previous
//
#include <hip/hip_runtime.h>
#include <hip/hip_fp16.h>
#include <math.h>

constexpr int H = 2048;
constexpr int W = 4096;
constexpr int RS = W * 3;   // floats per image row

// f16 RGBX window: 12 rows x 72 used px (stride 80), 8 B/px -> 7.5 KB LDS
constexpr int WIN_ROWS = 12;
constexpr int WIN_PXS  = 80;
constexpr int WIN_USED = 72;

__device__ __forceinline__ float k_inner(float t) {   // t in [0,1]
    return fmaf(fmaf(1.5f, t, -2.5f), t * t, 1.0f);
}
__device__ __forceinline__ float k_outer(float t) {   // t in [1,2]
    return fmaf(fmaf(fmaf(-0.5f, t, 2.5f), t, -4.0f), t, 2.0f);
}
__device__ __forceinline__ float cubic_w(float t) {
    float at = fabsf(t);
    if (at <= 1.0f) return k_inner(at);
    if (at < 2.0f)  return k_outer(at);
    return 0.0f;
}

__device__ __forceinline__ void row_cy(int h, const float* __restrict__ dctrl, float cy[6]) {
    float u = (float)(2 * h) / (float)(H - 1);
    float i0 = floorf(u);
    float by0 = 0.f, by1 = 0.f, by2 = 0.f;
#pragma unroll
    for (int k = -1; k < 3; ++k) {
        float tap = i0 + (float)k;
        float wt = cubic_w(u - tap);
        int tc = (int)tap;
        tc = tc < 0 ? 0 : (tc > 2 ? 2 : tc);
        if (tc == 0) by0 += wt; else if (tc == 1) by1 += wt; else by2 += wt;
    }
#pragma unroll
    for (int x = 0; x < 3; ++x) {
        cy[x]     = 5.0f * (by0 * dctrl[x]     + by1 * dctrl[3 + x]  + by2 * dctrl[6 + x]);
        cy[3 + x] = 5.0f * (by0 * dctrl[9 + x] + by1 * dctrl[12 + x] + by2 * dctrl[15 + x]);
    }
}

__device__ __forceinline__ void bx3(int w, float& b0, float& b1, float& b2) {
    float u = (float)w * (2.0f / 4095.0f);
    bool hiu = u >= 1.0f;
    float s = u - (hiu ? 1.0f : 0.0f);
    float o1 = k_outer(1.0f + s);
    float is = k_inner(s);
    float i1 = k_inner(1.0f - s);
    float o2 = k_outer(2.0f - s);
    b0 = hiu ? o1 : (o1 + is);
    b1 = hiu ? is : i1;
    b2 = hiu ? (i1 + o2) : o2;
}

__device__ __forceinline__ __half2 as_h2(unsigned u) {
    union { unsigned u; __half2 h; } c; c.u = u; return c.h;
}
__device__ __forceinline__ unsigned as_u32(__half2 h) {
    union { unsigned u; __half2 h; } c; c.h = h; return c.u;
}

// Block = 64x4 px tile (wave = one output row of 64 px).
__global__ __launch_bounds__(256)
void elastic_warp_kernel(const float* __restrict__ img,
                         const float* __restrict__ dctrl,  // (2,3,3) unscaled
                         float* __restrict__ out) {
    int x0 = blockIdx.x << 6;
    int y0 = blockIdx.y << 2;
    int t = threadIdx.x;
    int r = t >> 6;            // 0..3 tile row
    int w = x0 + (t & 63);
    int h = y0 + r;

    __shared__ float s_cy[4][6];
    __shared__ int   s_base[2];
    __shared__ int   s_flag[4];
    __shared__ uint2 s_win[WIN_ROWS][WIN_PXS];   // 7.5 KB, f16 RGBX

    if (t < 4) {
        float cy[6];
        row_cy(y0 + t, dctrl, cy);
#pragma unroll
        for (int j = 0; j < 6; ++j) s_cy[t][j] = cy[j];
        if (t == 0) {
            float b0, b1, b2; bx3(x0, b0, b1, b2);
            float d0 = cy[0]*b0 + cy[1]*b1 + cy[2]*b2;
            float d1 = cy[3]*b0 + cy[4]*b1 + cy[5]*b2;
            s_base[0] = (int)floorf((float)y0 + d0);
            s_base[1] = (int)floorf((float)x0 + d1);
        }
    }
    __syncthreads();

    float cy0 = s_cy[r][0], cy1 = s_cy[r][1], cy2 = s_cy[r][2];
    float cy3 = s_cy[r][3], cy4 = s_cy[r][4], cy5 = s_cy[r][5];
    int base_iy = s_base[0], base_ix = s_base[1];

    float bx0, bx1, bx2; bx3(w, bx0, bx1, bx2);
    float d0 = cy0*bx0 + cy1*bx1 + cy2*bx2;
    float d1 = cy3*bx0 + cy4*bx1 + cy5*bx2;

    float yy = (float)h + d0;
    float xx = (float)w + d1;
    float fly = floorf(yy), flx = floorf(xx);
    float fy = yy - fly, fx = xx - flx;
    int iy0 = (int)fly, ix0 = (int)flx;

    // window anchor (block-uniform)
    int yb = base_iy - 2;                 // staged rows yb .. yb+11
    int xb = base_ix - 2;                 // staged cols xb .. xb+71

    int ry0 = iy0 - 1 - yb;               // first tap row within window
    int cxp = ix0 - 1 - xb;               // first tap col (px) within window

    // xb+72 <= W-1 leaves room for the 4-byte over-read of the staging float4
    bool uok = (yb >= 0) & (yb + WIN_ROWS - 1 <= H - 1) & (xb >= 0) & (xb + WIN_USED <= W - 1);
    bool lok = (ry0 >= 0) & (ry0 <= 8) & (cxp >= 0) & (cxp <= 68);
    int wflag = __all(uok & lok);
    if ((t & 63) == 0) s_flag[t >> 6] = wflag;
    __syncthreads();
    bool fast = s_flag[0] && s_flag[1] && s_flag[2] && s_flag[3];

    float wy0 = k_outer(1.0f + fy), wy1 = k_inner(fy), wy2 = k_inner(1.0f - fy), wy3 = k_outer(2.0f - fy);
    float wx0 = k_outer(1.0f + fx), wx1 = k_inner(fx), wx2 = k_inner(1.0f - fx), wx3 = k_outer(2.0f - fx);

    float acc0 = 0.f, acc1 = 0.f, acc2 = 0.f;

    if (fast) {
        // ---- cooperative stage: 864 px, f32 interleaved -> f16 RGBX ----
        const float* gbase = img + yb * RS + xb * 3;
#pragma unroll
        for (int it = 0; it < 4; ++it) {
            int idx = t + (it << 8);
            if (idx < WIN_ROWS * WIN_USED) {
                int row = idx / WIN_USED;
                int col = idx - row * WIN_USED;
                const float* p = gbase + row * RS + col * 3;
                float4 v = *(const float4*)p;          // 12 B used + 4 B over-read
                __half2 rg = __floats2half2_rn(v.x, v.y);
                __half2 bz = __floats2half2_rn(v.z, 0.0f);
                uint2 u;
                u.x = as_u32(rg);
                u.y = as_u32(bz);
                s_win[row][col] = u;
            }
        }
        __syncthreads();

        // ---- gather: 4 rows x 4 consecutive uint2 -> 16 ds_read_b64 ----
        uint2 m00 = s_win[ry0    ][cxp], m01 = s_win[ry0    ][cxp+1], m02 = s_win[ry0    ][cxp+2], m03 = s_win[ry0    ][cxp+3];
        uint2 m10 = s_win[ry0 + 1][cxp], m11 = s_win[ry0 + 1][cxp+1], m12 = s_win[ry0 + 1][cxp+2], m13 = s_win[ry0 + 1][cxp+3];
        uint2 m20 = s_win[ry0 + 2][cxp], m21 = s_win[ry0 + 2][cxp+1], m22 = s_win[ry0 + 2][cxp+2], m23 = s_win[ry0 + 2][cxp+3];
        uint2 m30 = s_win[ry0 + 3][cxp], m31 = s_win[ry0 + 3][cxp+1], m32 = s_win[ry0 + 3][cxp+2], m33 = s_win[ry0 + 3][cxp+3];

        __half2 wxh0 = __float2half2_rn(wx0);
        __half2 wxh1 = __float2half2_rn(wx1);
        __half2 wxh2 = __float2half2_rn(wx2);
        __half2 wxh3 = __float2half2_rn(wx3);

#define ROWF16(mA, mB, mC, mD, ay)                                   \
        { __half2 iRG = __hmul2(wxh0, as_h2(mA.x));                  \
          __half2 iBZ = __hmul2(wxh0, as_h2(mA.y));                  \
          iRG = __hfma2(wxh1, as_h2(mB.x), iRG);                     \
          iBZ = __hfma2(wxh1, as_h2(mB.y), iBZ);                     \
          iRG = __hfma2(wxh2, as_h2(mC.x), iRG);                     \
          iBZ = __hfma2(wxh2, as_h2(mC.y), iBZ);                     \
          iRG = __hfma2(wxh3, as_h2(mD.x), iRG);                     \
          iBZ = __hfma2(wxh3, as_h2(mD.y), iBZ);                     \
          acc0 = fmaf(ay, __low2float(iRG), acc0);                   \
          acc1 = fmaf(ay, __high2float(iRG), acc1);                  \
          acc2 = fmaf(ay, __low2float(iBZ), acc2); }

        ROWF16(m00, m01, m02, m03, wy0)
        ROWF16(m10, m11, m12, m13, wy1)
        ROWF16(m20, m21, m22, m23, wy2)
        ROWF16(m30, m31, m32, m33, wy3)
#undef ROWF16
    } else {
        // uniform slow path: per-px clamped global gather (f32 exact)
        float wy[4] = {wy0, wy1, wy2, wy3};
        float wx[4] = {wx0, wx1, wx2, wx3};
#pragma unroll
        for (int a = 0; a < 4; ++a) {
            int ty = iy0 + a - 1;
            ty = ty < 0 ? 0 : (ty > H - 1 ? H - 1 : ty);
            int rowoff = ty * RS;
            float ay = wy[a];
#pragma unroll
            for (int b = 0; b < 4; ++b) {
                int tx = ix0 + b - 1;
                tx = tx < 0 ? 0 : (tx > W - 1 ? W - 1 : tx);
                float wgt = ay * wx[b];
                const float* p = img + rowoff + tx * 3;
                acc0 += wgt * p[0];
                acc1 += wgt * p[1];
                acc2 += wgt * p[2];
            }
        }
    }

    int oo = (h * W + w) * 3;
    out[oo + 0] = acc0;
    out[oo + 1] = acc1;
    out[oo + 2] = acc2;
}

extern "C" void kernel_launch(void* const* d_in, const int* in_sizes, int n_in,
                              void* d_out, int out_size, void* d_ws, size_t ws_size,
                              hipStream_t stream) {
    const float* img   = (const float*)d_in[0];
    const float* dctrl = (const float*)d_in[1];
    float* out = (float*)d_out;

    dim3 grid(W / 64, H / 4);
    elastic_warp_kernel<<<grid, 256, 0, stream>>>(img, dctrl, out);
}

// Round 12
// 62.166 us; speedup vs baseline: 1.4347x; 1.2349x over previous
//
#include <hip/hip_runtime.h>
#include <math.h>

constexpr int H = 2048;
constexpr int W = 4096;
constexpr int RS = W * 3;   // floats per image row

// Keys cubic (a = -0.5) pieces on known-positive argument.
__device__ __forceinline__ float k_inner(float t) {   // t in [0,1]:  1.5t^3 - 2.5t^2 + 1
    return fmaf(fmaf(1.5f, t, -2.5f), t * t, 1.0f);
}
__device__ __forceinline__ float k_outer(float t) {   // t in [1,2]: -0.5t^3 + 2.5t^2 - 4t + 2
    return fmaf(fmaf(fmaf(-0.5f, t, 2.5f), t, -4.0f), t, 2.0f);
}
__device__ __forceinline__ float cubic_w(float t) {
    float at = fabsf(t);
    if (at <= 1.0f) return k_inner(at);
    if (at < 2.0f)  return k_outer(at);
    return 0.0f;
}

// Block covers a 64x16 px region = 4 tiles of 16x16, processed in a loop.
// Wave lane layout (per tile): xi = lane&15 (column), gi = lane>>4;
// row r = wave*4 + gi. One wave-gather spans 4 short row segments (R8 geometry).
__global__ __launch_bounds__(256)
void elastic_warp_kernel(const float* __restrict__ img,
                         const float* __restrict__ dctrl,  // (2,3,3) unscaled
                         float* __restrict__ out) {
    int x0r = blockIdx.x << 6;    // 64-px x-region
    int y0  = blockIdx.y << 4;    // 16-px y-band

    int t = threadIdx.x;
    int lane = t & 63;
    int wave = t >> 6;
    int xi = lane & 15;
    int gi = lane >> 4;
    int r  = (wave << 2) + gi;    // row within band, 0..15

    // ---- per-band-row uniform: cy = 5 * (by^T . D), 16 rows, computed once ----
    __shared__ float s_cy[16][6];
    if (t < 16) {
        int hh = y0 + t;
        float u = (float)(2 * hh) / (float)(H - 1);
        float i0 = floorf(u);
        float by0 = 0.f, by1 = 0.f, by2 = 0.f;
#pragma unroll
        for (int k = -1; k < 3; ++k) {
            float tap = i0 + (float)k;
            float wt = cubic_w(u - tap);
            int tc = (int)tap;
            tc = tc < 0 ? 0 : (tc > 2 ? 2 : tc);
            if (tc == 0) by0 += wt; else if (tc == 1) by1 += wt; else by2 += wt;
        }
#pragma unroll
        for (int x = 0; x < 3; ++x) {
            s_cy[t][x]     = 5.0f * (by0 * dctrl[x]     + by1 * dctrl[3 + x]  + by2 * dctrl[6 + x]);
            s_cy[t][3 + x] = 5.0f * (by0 * dctrl[9 + x] + by1 * dctrl[12 + x] + by2 * dctrl[15 + x]);
        }
    }
    __syncthreads();

    // hoisted per-thread invariants (same image row for all 4 tiles)
    int h = y0 + r;
    float hf = (float)h;
    float cy0 = s_cy[r][0], cy1 = s_cy[r][1], cy2 = s_cy[r][2];
    float cy3 = s_cy[r][3], cy4 = s_cy[r][4], cy5 = s_cy[r][5];
    int rowbase = h * W;

#pragma unroll
    for (int it = 0; it < 4; ++it) {
        int w = x0r + (it << 4) + xi;

        // ---- per-px spline bx (piecewise, branchless) ----
        float u = (float)w * (2.0f / 4095.0f);
        bool hiu = u >= 1.0f;
        float s = u - (hiu ? 1.0f : 0.0f);
        float o1 = k_outer(1.0f + s);
        float is = k_inner(s);
        float i1 = k_inner(1.0f - s);
        float o2 = k_outer(2.0f - s);
        float bx0 = hiu ? o1 : (o1 + is);
        float bx1 = hiu ? is : i1;
        float bx2 = hiu ? (i1 + o2) : o2;

        float d0 = cy0 * bx0 + cy1 * bx1 + cy2 * bx2;
        float d1 = cy3 * bx0 + cy4 * bx1 + cy5 * bx2;

        // ---- sample coordinates ----
        float yy = hf + d0;
        float xx = (float)w + d1;
        float iy0f = floorf(yy);
        float ix0f = floorf(xx);
        float fy = yy - iy0f;
        float fx = xx - ix0f;
        int iy0 = (int)iy0f;
        int ix0 = (int)ix0f;

        float wy0 = k_outer(1.0f + fy), wy1 = k_inner(fy), wy2 = k_inner(1.0f - fy), wy3 = k_outer(2.0f - fy);
        float wx0 = k_outer(1.0f + fx), wx1 = k_inner(fx), wx2 = k_inner(1.0f - fx), wx3 = k_outer(2.0f - fx);

        float acc0, acc1, acc2;

        bool interior = (iy0 >= 1) & (iy0 <= H - 3) & (ix0 >= 1) & (ix0 <= W - 3);
        if (interior) {
            int off = ((iy0 - 1) * W + (ix0 - 1)) * 3;
            const float* b0 = img + off;
            const float* b1 = b0 + RS;
            const float* b2 = b1 + RS;
            const float* b3 = b2 + RS;

            float4 v00 = ((const float4*)b0)[0];
            float4 v01 = ((const float4*)b0)[1];
            float4 v02 = ((const float4*)b0)[2];
            float4 v10 = ((const float4*)b1)[0];
            float4 v11 = ((const float4*)b1)[1];
            float4 v12 = ((const float4*)b1)[2];
            float4 v20 = ((const float4*)b2)[0];
            float4 v21 = ((const float4*)b2)[1];
            float4 v22 = ((const float4*)b2)[2];
            float4 v30 = ((const float4*)b3)[0];
            float4 v31 = ((const float4*)b3)[1];
            float4 v32 = ((const float4*)b3)[2];

            // factorized: per-row horizontal 4-tap dot, then vertical combine
            float t00 = fmaf(wx0, v00.x, fmaf(wx1, v00.w, fmaf(wx2, v01.z, wx3 * v02.y)));
            float t01 = fmaf(wx0, v00.y, fmaf(wx1, v01.x, fmaf(wx2, v01.w, wx3 * v02.z)));
            float t02 = fmaf(wx0, v00.z, fmaf(wx1, v01.y, fmaf(wx2, v02.x, wx3 * v02.w)));

            float t10 = fmaf(wx0, v10.x, fmaf(wx1, v10.w, fmaf(wx2, v11.z, wx3 * v12.y)));
            float t11 = fmaf(wx0, v10.y, fmaf(wx1, v11.x, fmaf(wx2, v11.w, wx3 * v12.z)));
            float t12 = fmaf(wx0, v10.z, fmaf(wx1, v11.y, fmaf(wx2, v12.x, wx3 * v12.w)));

            float t20 = fmaf(wx0, v20.x, fmaf(wx1, v20.w, fmaf(wx2, v21.z, wx3 * v22.y)));
            float t21 = fmaf(wx0, v20.y, fmaf(wx1, v21.x, fmaf(wx2, v21.w, wx3 * v22.z)));
            float t22 = fmaf(wx0, v20.z, fmaf(wx1, v21.y, fmaf(wx2, v22.x, wx3 * v22.w)));

            float t30 = fmaf(wx0, v30.x, fmaf(wx1, v30.w, fmaf(wx2, v31.z, wx3 * v32.y)));
            float t31 = fmaf(wx0, v30.y, fmaf(wx1, v31.x, fmaf(wx2, v31.w, wx3 * v32.z)));
            float t32 = fmaf(wx0, v30.z, fmaf(wx1, v31.y, fmaf(wx2, v32.x, wx3 * v32.w)));

            acc0 = fmaf(wy0, t00, fmaf(wy1, t10, fmaf(wy2, t20, wy3 * t30)));
            acc1 = fmaf(wy0, t01, fmaf(wy1, t11, fmaf(wy2, t21, wy3 * t31)));
            acc2 = fmaf(wy0, t02, fmaf(wy1, t12, fmaf(wy2, t22, wy3 * t32)));
        } else {
            acc0 = 0.f; acc1 = 0.f; acc2 = 0.f;
            float wy[4] = {wy0, wy1, wy2, wy3};
            float wx[4] = {wx0, wx1, wx2, wx3};
#pragma unroll
            for (int a = 0; a < 4; ++a) {
                int ty = iy0 + a - 1;
                ty = ty < 0 ? 0 : (ty > H - 1 ? H - 1 : ty);
                int rowoff = ty * RS;
                float ay = wy[a];
#pragma unroll
                for (int b = 0; b < 4; ++b) {
                    int tx = ix0 + b - 1;
                    tx = tx < 0 ? 0 : (tx > W - 1 ? W - 1 : tx);
                    float wgt = ay * wx[b];
                    const float* p = img + rowoff + tx * 3;
                    acc0 += wgt * p[0];
                    acc1 += wgt * p[1];
                    acc2 += wgt * p[2];
                }
            }
        }

        int oo = (rowbase + w) * 3;
        __builtin_nontemporal_store(acc0, out + oo);
        __builtin_nontemporal_store(acc1, out + oo + 1);
        __builtin_nontemporal_store(acc2, out + oo + 2);
    }
}

extern "C" void kernel_launch(void* const* d_in, const int* in_sizes, int n_in,
                              void* d_out, int out_size, void* d_ws, size_t ws_size,
                              hipStream_t stream) {
    const float* img   = (const float*)d_in[0];
    const float* dctrl = (const float*)d_in[1];
    float* out = (float*)d_out;

    dim3 grid(W / 64, H / 16);   // 64x16 px per block
    elastic_warp_kernel<<<grid, 256, 0, stream>>>(img, dctrl, out);
}